// Round 1
// 194.590 us; speedup vs baseline: 1.0442x; 1.0442x over previous
//
#include <hip/hip_runtime.h>

// Problem shapes (fixed by setup_inputs):
//   count_logits    : (16, 21)           fp32   -> d_in[0]
//   pred_heatmaps   : (16,20,17,64,64)   fp32   -> d_in[1]  (89.13 MB)
//   pred_conf_logits: (16, 20)           fp32   -> d_in[2]
//   gt_heatmaps     : (16,20,17,64,64)   fp32   -> d_in[3]  (89.13 MB)
//   count           : (16,)              int32  -> d_in[4]
//   mask            : (16, 20)           int32  -> d_in[5]
// Output: scalar total loss (fp32).

#define B_      16
#define P_      20
#define NBP     (B_ * P_)          // 320 slices
#define KHW     (17 * 64 * 64)     // 69632 floats per slice
#define KHW4    (KHW / 4)          // 17408 float4 per slice
#define KHW8    (KHW / 8)          // 8704 32B-units per slice (8704 % 64 == 0 -> wave-uniform slice)
#define NBLOCKS 2048               // 8 blocks/CU * 256 CUs, full occupancy in one round
#define NTHREADS 256

#define PEAK_THRESH 0.2f
#define PEAK_WEIGHT 5.0f

__device__ __forceinline__ float wdiff4(const float4 p, const float4 g) {
    float d, w, a;
    d = p.x - g.x; w = (g.x > PEAK_THRESH) ? PEAK_WEIGHT : 1.0f; a  = d * d * w;
    d = p.y - g.y; w = (g.y > PEAK_THRESH) ? PEAK_WEIGHT : 1.0f; a += d * d * w;
    d = p.z - g.z; w = (g.z > PEAK_THRESH) ? PEAK_WEIGHT : 1.0f; a += d * d * w;
    d = p.w - g.w; w = (g.w > PEAK_THRESH) ? PEAK_WEIGHT : 1.0f; a += d * d * w;
    return a;
}

__global__ __launch_bounds__(NTHREADS)
void hm_partial_kernel(const float4* __restrict__ pred,
                       const float4* __restrict__ gt,
                       const int*    __restrict__ mask,
                       float*        __restrict__ partial) {
    // --- mask compaction: one wave builds the active-slice list in LDS ---
    __shared__ int s_act[NBP];
    __shared__ int s_cnt;
    const int lane = threadIdx.x & 63;
    if (threadIdx.x < 64) {                       // wave 0, all 64 lanes active
        int base = 0;
        #pragma unroll
        for (int r = 0; r < NBP / 64; ++r) {      // 5 rounds of 64
            const int idx = r * 64 + lane;
            const bool m = (mask[idx] != 0);
            const unsigned long long bal = __ballot(m);
            if (m) {
                const int pos = __popcll(bal & ((1ull << lane) - 1ull));
                s_act[base + pos] = idx;
            }
            base += __popcll(bal);
        }
        if (lane == 0) s_cnt = base;
    }
    __syncthreads();

    // --- branch-free streaming over ACTIVE elements only, 32 B/lane/iter ---
    const int total = s_cnt * KHW8;               // 32B-units of active work
    const int stride = gridDim.x * blockDim.x;
    float acc = 0.0f;
    for (int j = blockIdx.x * blockDim.x + threadIdx.x; j < total; j += stride) {
        const int slice = j / KHW8;               // wave-uniform (KHW8 % 64 == 0)
        const int off   = j - slice * KHW8;
        const int b4    = (s_act[slice] * KHW8 + off) * 2;  // float4 index, fits int
        const float4 p0 = pred[b4], p1 = pred[b4 + 1];      // 4 independent 16B loads
        const float4 g0 = gt[b4],   g1 = gt[b4 + 1];
        acc += wdiff4(p0, g0);
        acc += wdiff4(p1, g1);
    }

    // --- wave reduce (width 64) then block reduce ---
    #pragma unroll
    for (int off = 32; off > 0; off >>= 1) acc += __shfl_down(acc, off);

    __shared__ float s[NTHREADS / 64];
    if ((threadIdx.x & 63) == 0) s[threadIdx.x >> 6] = acc;
    __syncthreads();
    if (threadIdx.x == 0) {
        float t = 0.0f;
        #pragma unroll
        for (int w = 0; w < NTHREADS / 64; ++w) t += s[w];
        partial[blockIdx.x] = t;
    }
}

__global__ __launch_bounds__(64)
void finalize_kernel(const float* __restrict__ partial,
                     const float* __restrict__ count_logits,
                     const int*   __restrict__ count,
                     const float* __restrict__ conf_logits,
                     const int*   __restrict__ mask,
                     float*       __restrict__ out) {
    const int lane = threadIdx.x;  // 64 threads, one wave

    // 1) heatmap diff sum over block partials
    float ds = 0.0f;
    for (int i = lane; i < NBLOCKS; i += 64) ds += partial[i];

    // 2) mask sum + focal loss over the 320 conf logits
    float ms = 0.0f, fs = 0.0f;
    for (int i = lane; i < NBP; i += 64) {
        const float t = (float)mask[i];
        ms += t;
        const float l   = conf_logits[i];
        const float bce = fmaxf(l, 0.0f) - l * t + log1pf(expf(-fabsf(l)));
        const float pt  = expf(-bce);
        const float om  = 1.0f - pt;
        fs += om * om * bce;     // gamma = 2
    }

    // 3) count cross-entropy: lane b < 16 handles row b (21 logits)
    float ce = 0.0f;
    if (lane < B_) {
        const float* row = count_logits + lane * (P_ + 1);
        float mx = row[0];
        #pragma unroll
        for (int j = 1; j < P_ + 1; ++j) mx = fmaxf(mx, row[j]);
        float se = 0.0f;
        #pragma unroll
        for (int j = 0; j < P_ + 1; ++j) se += expf(row[j] - mx);
        const float lse = mx + logf(se);
        ce = -(row[count[lane]] - lse);
    }

    // wave reduce all four
    #pragma unroll
    for (int off = 32; off > 0; off >>= 1) {
        ds += __shfl_down(ds, off);
        ms += __shfl_down(ms, off);
        fs += __shfl_down(fs, off);
        ce += __shfl_down(ce, off);
    }

    if (lane == 0) {
        const float loss_count = ce / (float)B_;
        const float loss_conf  = fs / (float)NBP;
        const float hm         = ds / (ms * (float)KHW + 1e-6f);
        const float loss_hm    = (ms > 0.0f) ? hm : 0.0f;
        out[0] = 1.0f * loss_count + 10.0f * loss_hm + 1.5f * loss_conf;
    }
}

extern "C" void kernel_launch(void* const* d_in, const int* in_sizes, int n_in,
                              void* d_out, int out_size, void* d_ws, size_t ws_size,
                              hipStream_t stream) {
    const float* count_logits = (const float*)d_in[0];
    const float* pred_hm      = (const float*)d_in[1];
    const float* conf_logits  = (const float*)d_in[2];
    const float* gt_hm        = (const float*)d_in[3];
    const int*   count        = (const int*)d_in[4];
    const int*   mask         = (const int*)d_in[5];
    float*       out          = (float*)d_out;
    float*       partial      = (float*)d_ws;   // NBLOCKS floats

    hm_partial_kernel<<<NBLOCKS, NTHREADS, 0, stream>>>(
        (const float4*)pred_hm, (const float4*)gt_hm, mask, partial);

    finalize_kernel<<<1, 64, 0, stream>>>(
        partial, count_logits, count, conf_logits, mask, out);
}